// Round 1
// baseline (566.300 us; speedup 1.0000x reference)
//
#include <hip/hip_runtime.h>
#include <hip/hip_bf16.h>
#include <cstdint>
#include <cstddef>

// Shapes: B=2, S=512, C=25, H=768, 2H=1536, 3H=2304, 4H=3072
#define BB 2
#define SS 512
#define CC 25
#define HH 768
#define H2 1536
#define H3 2304
#define H4 3072

typedef __attribute__((ext_vector_type(8))) short bf16x8;   // 8 bf16 = 4 VGPRs
typedef __attribute__((ext_vector_type(4))) float f32x4;

#define DEVINL static __device__ __forceinline__

DEVINL unsigned short f2bf(float f) {
  union { float f; unsigned u; } v; v.f = f;
  unsigned r = v.u + 0x7FFF + ((v.u >> 16) & 1);  // RNE
  return (unsigned short)(r >> 16);
}
DEVINL float bf2f(unsigned short b) {
  union { unsigned u; float f; } v; v.u = ((unsigned)b) << 16; return v.f;
}

DEVINL void async16(const void* g, void* l) {
  __builtin_amdgcn_global_load_lds(
      (const __attribute__((address_space(1))) void*)g,
      (__attribute__((address_space(3))) void*)l, 16, 0, 0);
}

// ---------------- small kernels ----------------

__global__ void k_f32_to_bf16(const float* __restrict__ in,
                              unsigned short* __restrict__ out, int n) {
  int i = blockIdx.x * 256 + threadIdx.x;
  if (i < n) out[i] = f2bf(in[i]);
}

// out[n][k] = bf16(in[k][n]); in is R x C fp32, out is C x R bf16
__global__ void k_transpose_bf16(const float* __restrict__ in,
                                 unsigned short* __restrict__ out,
                                 int R, int C) {
  __shared__ float tile[32][33];
  int c0 = blockIdx.x * 32, r0 = blockIdx.y * 32;
  int tx = threadIdx.x, ty = threadIdx.y;  // block (32,8)
#pragma unroll
  for (int i = 0; i < 4; i++)
    tile[ty + i * 8][tx] = in[(size_t)(r0 + ty + i * 8) * C + c0 + tx];
  __syncthreads();
#pragma unroll
  for (int i = 0; i < 4; i++)
    out[(size_t)(c0 + ty + i * 8) * R + r0 + tx] = f2bf(tile[tx][ty + i * 8]);
}

// X[bc][s][h] = tb[b][s][h] * lb[b][c][h]   (tb = tp[:,768:], lb = lp[:,768:])
__global__ void k_make_x(const unsigned short* __restrict__ tp,
                         const unsigned short* __restrict__ lp,
                         unsigned short* __restrict__ X) {
  int idx = blockIdx.x * 256 + threadIdx.x;   // total = 50*512*96
  if (idx >= CC * BB * SS * (HH / 8)) return;
  int hc = idx % (HH / 8);
  int rest = idx / (HH / 8);
  int s = rest % SS;
  int bc = rest / SS;
  int b = bc / CC;
  const bf16x8 tv = *(const bf16x8*)&tp[(size_t)(b * SS + s) * H2 + HH + hc * 8];
  const bf16x8 lv = *(const bf16x8*)&lp[(size_t)bc * H2 + HH + hc * 8];
  bf16x8 o;
#pragma unroll
  for (int j = 0; j < 8; j++) {
    float f = bf2f((unsigned short)tv[j]) * bf2f((unsigned short)lv[j]);
    o[j] = (short)f2bf(f);
  }
  *(bf16x8*)&X[(size_t)(bc * SS + s) * HH + hc * 8] = o;
}

__global__ void k_init_out(float* __restrict__ out, const float* __restrict__ b2, int n) {
  int i = blockIdx.x * 256 + threadIdx.x;
  if (i < n) out[i] = b2[i % 3];
}

// ---------------- 128x128 bf16 MFMA GEMM ----------------
// A: M x K row-major bf16 (lda), Bt: N x K row-major bf16 (ldb)  [i.e. B^T]
// MODE 0: Cbf[row*ldc+col] = bf16(acc + bias[col])
// MODE 1: Cf [row*ldc+col] = acc
// MODE 2: scorer epilogue: v = acc + base[(b*512+s)*3072+f] + al[bc*3072+f] + b1[f];
//         relu; out[((b*512+s)*25+c)*3+j] += sum_f v*W2[f][j]  (atomic)

template <int MODE>
__global__ __launch_bounds__(256, 2) void gemm128(
    const unsigned short* __restrict__ A, int lda, size_t strideAz,
    const unsigned short* __restrict__ Bt, int ldb,
    int M, int K,
    unsigned short* __restrict__ Cbf, float* __restrict__ Cf, int ldc,
    const float* __restrict__ bias,
    const float* __restrict__ base, const float* __restrict__ al,
    const float* __restrict__ b1, const float* __restrict__ W2,
    float* __restrict__ out) {
  __shared__ __align__(16) unsigned short As[512 * 8];  // [kc][row][8]
  __shared__ __align__(16) unsigned short Bs[512 * 8];  // [kc][nrow][8]

  const int tid = threadIdx.x;
  const int lane = tid & 63;
  const int wave = tid >> 6;
  const int q = lane >> 4;
  const int li = lane & 15;
  const int wm = (wave >> 1) * 64;
  const int wn = (wave & 1) * 64;

  const int n0 = blockIdx.x * 128;
  const int m0 = blockIdx.y * 128;
  const int bc = blockIdx.z;

  const unsigned short* Ab = A + (size_t)bc * strideAz;

  // staging assignment: slot = t*256 + tid, t=0,1 ; slot -> (kc = slot>>7, r = slot&127)
  const int s0i = tid, s1i = 256 + tid;
  const int kc0 = s0i >> 7, r0 = s0i & 127;
  const int kc1 = s1i >> 7, r1 = s1i & 127;
  const int ra0 = min(m0 + r0, M - 1);
  const int ra1 = min(m0 + r1, M - 1);
  const unsigned short* gA0 = Ab + (size_t)ra0 * lda + kc0 * 8;
  const unsigned short* gA1 = Ab + (size_t)ra1 * lda + kc1 * 8;
  const unsigned short* gB0 = Bt + (size_t)(n0 + r0) * ldb + kc0 * 8;
  const unsigned short* gB1 = Bt + (size_t)(n0 + r1) * ldb + kc1 * 8;
  unsigned short* lA0 = &As[s0i * 8];
  unsigned short* lA1 = &As[s1i * 8];
  unsigned short* lB0 = &Bs[s0i * 8];
  unsigned short* lB1 = &Bs[s1i * 8];

  f32x4 acc[4][4];
#pragma unroll
  for (int i = 0; i < 4; i++)
#pragma unroll
    for (int j = 0; j < 4; j++) acc[i][j] = (f32x4){0.f, 0.f, 0.f, 0.f};

  for (int k0 = 0; k0 < K; k0 += 32) {
    async16(gA0 + k0, lA0);
    async16(gA1 + k0, lA1);
    async16(gB0 + k0, lB0);
    async16(gB1 + k0, lB1);
    __syncthreads();

    bf16x8 af[4], bb[4];
#pragma unroll
    for (int mi = 0; mi < 4; mi++)
      af[mi] = *(const bf16x8*)&As[(q * 128 + wm + mi * 16 + li) * 8];
#pragma unroll
    for (int ni = 0; ni < 4; ni++)
      bb[ni] = *(const bf16x8*)&Bs[(q * 128 + wn + ni * 16 + li) * 8];
#pragma unroll
    for (int mi = 0; mi < 4; mi++)
#pragma unroll
      for (int ni = 0; ni < 4; ni++)
        acc[mi][ni] = __builtin_amdgcn_mfma_f32_16x16x32_bf16(
            af[mi], bb[ni], acc[mi][ni], 0, 0, 0);
    __syncthreads();
  }

  // ---------------- epilogues ----------------
  if (MODE == 0) {
#pragma unroll
    for (int mi = 0; mi < 4; mi++)
#pragma unroll
      for (int r = 0; r < 4; r++) {
        int row = m0 + wm + mi * 16 + q * 4 + r;
        if (row < M) {
#pragma unroll
          for (int ni = 0; ni < 4; ni++) {
            int col = n0 + wn + ni * 16 + li;
            Cbf[(size_t)row * ldc + col] = f2bf(acc[mi][ni][r] + bias[col]);
          }
        }
      }
  } else if (MODE == 1) {
#pragma unroll
    for (int mi = 0; mi < 4; mi++)
#pragma unroll
      for (int r = 0; r < 4; r++) {
        int row = m0 + wm + mi * 16 + q * 4 + r;
        if (row < M) {
#pragma unroll
          for (int ni = 0; ni < 4; ni++) {
            int col = n0 + wn + ni * 16 + li;
            Cf[(size_t)row * ldc + col] = acc[mi][ni][r];
          }
        }
      }
  } else {
    const int b = bc / CC, c = bc % CC;
    float alb[4], w20[4], w21[4], w22[4];
    int fcol[4];
#pragma unroll
    for (int ni = 0; ni < 4; ni++) {
      int f = n0 + wn + ni * 16 + li;
      fcol[ni] = f;
      alb[ni] = al[(size_t)bc * H4 + f] + b1[f];
      w20[ni] = W2[f * 3 + 0];
      w21[ni] = W2[f * 3 + 1];
      w22[ni] = W2[f * 3 + 2];
    }
#pragma unroll
    for (int mi = 0; mi < 4; mi++)
#pragma unroll
      for (int r = 0; r < 4; r++) {
        int s = m0 + wm + mi * 16 + q * 4 + r;
        const float* brow = base + (size_t)(b * SS + s) * H4;
        float s0 = 0.f, s1 = 0.f, s2 = 0.f;
#pragma unroll
        for (int ni = 0; ni < 4; ni++) {
          float v = acc[mi][ni][r] + brow[fcol[ni]] + alb[ni];
          v = fmaxf(v, 0.f);
          s0 = fmaf(v, w20[ni], s0);
          s1 = fmaf(v, w21[ni], s1);
          s2 = fmaf(v, w22[ni], s2);
        }
#pragma unroll
        for (int off = 1; off < 16; off <<= 1) {
          s0 += __shfl_xor(s0, off);
          s1 += __shfl_xor(s1, off);
          s2 += __shfl_xor(s2, off);
        }
        if (li == 0) {
          float* op = out + (size_t)((b * SS + s) * CC + c) * 3;
          atomicAdd(op + 0, s0);
          atomicAdd(op + 1, s1);
          atomicAdd(op + 2, s2);
        }
      }
  }
}

// ---------------- host launch ----------------

extern "C" void kernel_launch(void* const* d_in, const int* in_sizes, int n_in,
                              void* d_out, int out_size, void* d_ws, size_t ws_size,
                              hipStream_t stream) {
  (void)in_sizes; (void)n_in; (void)ws_size;
  const float* token = (const float*)d_in[0];  // (2,512,768)
  const float* label = (const float*)d_in[1];  // (2,25,768)
  const float* Wt    = (const float*)d_in[2];  // (768,1536)
  const float* bt    = (const float*)d_in[3];
  const float* Wl    = (const float*)d_in[4];  // (768,1536)
  const float* bl    = (const float*)d_in[5];
  const float* W1    = (const float*)d_in[6];  // (2304,3072)
  const float* b1    = (const float*)d_in[7];
  const float* W2    = (const float*)d_in[8];  // (3072,3)
  const float* b2    = (const float*)d_in[9];
  float* out = (float*)d_out;

  char* p = (char*)d_ws;
  auto alloc = [&](size_t bytes) {
    char* r = p;
    p += (bytes + 255) & ~(size_t)255;
    return r;
  };
  unsigned short* Tbf  = (unsigned short*)alloc((size_t)BB * SS * HH * 2);
  unsigned short* Lbf  = (unsigned short*)alloc((size_t)BB * CC * HH * 2);
  unsigned short* WtT  = (unsigned short*)alloc((size_t)H2 * HH * 2);
  unsigned short* WlT  = (unsigned short*)alloc((size_t)H2 * HH * 2);
  unsigned short* W1T  = (unsigned short*)alloc((size_t)H4 * H3 * 2);  // [3072][2304]
  unsigned short* tpbf = (unsigned short*)alloc((size_t)BB * SS * H2 * 2);
  unsigned short* lpbf = (unsigned short*)alloc((size_t)BB * CC * H2 * 2);
  unsigned short* Xall = (unsigned short*)alloc((size_t)BB * CC * SS * HH * 2);
  float* base = (float*)alloc((size_t)BB * SS * H4 * 4);
  float* al   = (float*)alloc((size_t)BB * CC * H4 * 4);

  const int nT = BB * SS * HH;   // 786432
  const int nL = BB * CC * HH;   // 38400

  k_f32_to_bf16<<<(nT + 255) / 256, 256, 0, stream>>>(token, Tbf, nT);
  k_f32_to_bf16<<<(nL + 255) / 256, 256, 0, stream>>>(label, Lbf, nL);
  k_transpose_bf16<<<dim3(H2 / 32, HH / 32), dim3(32, 8), 0, stream>>>(Wt, WtT, HH, H2);
  k_transpose_bf16<<<dim3(H2 / 32, HH / 32), dim3(32, 8), 0, stream>>>(Wl, WlT, HH, H2);
  k_transpose_bf16<<<dim3(H4 / 32, H3 / 32), dim3(32, 8), 0, stream>>>(W1, W1T, H3, H4);

  // G1: tp = T @ Wt + bt   (M=1024, N=1536, K=768) -> bf16
  gemm128<0><<<dim3(H2 / 128, (BB * SS) / 128, 1), 256, 0, stream>>>(
      Tbf, HH, 0, WtT, HH, BB * SS, HH, tpbf, nullptr, H2, bt,
      nullptr, nullptr, nullptr, nullptr, nullptr);
  // G2: lp = L @ Wl + bl   (M=50 ragged, N=1536, K=768) -> bf16
  gemm128<0><<<dim3(H2 / 128, 1, 1), 256, 0, stream>>>(
      Lbf, HH, 0, WlT, HH, BB * CC, HH, lpbf, nullptr, H2, bl,
      nullptr, nullptr, nullptr, nullptr, nullptr);

  // X[bc,s,h] = tb*lb
  const int nX = BB * CC * SS * (HH / 8);
  k_make_x<<<(nX + 255) / 256, 256, 0, stream>>>(tpbf, lpbf, Xall);

  // G3: base = ta @ W1t   (M=1024, N=3072, K=768) -> fp32
  gemm128<1><<<dim3(H4 / 128, (BB * SS) / 128, 1), 256, 0, stream>>>(
      tpbf, H2, 0, W1T, H3, BB * SS, HH, nullptr, base, H4, nullptr,
      nullptr, nullptr, nullptr, nullptr, nullptr);
  // G4: al = la @ W1l   (M=50 ragged, N=3072, K=768) -> fp32
  gemm128<1><<<dim3(H4 / 128, 1, 1), 256, 0, stream>>>(
      lpbf, H2, 0, W1T + HH, H3, BB * CC, HH, nullptr, al, H4, nullptr,
      nullptr, nullptr, nullptr, nullptr, nullptr);

  // out = b2 broadcast
  k_init_out<<<(out_size + 255) / 256, 256, 0, stream>>>(out, b2, out_size);

  // G5: per (b,c): (tb.*lb) @ W1p, + base + al + b1, relu, @W2 -> atomic out
  gemm128<2><<<dim3(H4 / 128, SS / 128, BB * CC), 256, 0, stream>>>(
      Xall, HH, (size_t)SS * HH, W1T + H2, H3, SS, HH, nullptr, nullptr, 0,
      nullptr, base, al, b1, W2, out);
}

// Round 2
// 537.712 us; speedup vs baseline: 1.0532x; 1.0532x over previous
//
#include <hip/hip_runtime.h>
#include <hip/hip_bf16.h>
#include <cstdint>
#include <cstddef>

// Shapes: B=2, S=512, C=25, H=768, 2H=1536, 3H=2304, 4H=3072
#define BB 2
#define SS 512
#define CC 25
#define HH 768
#define H2 1536
#define H3 2304
#define H4 3072

typedef __attribute__((ext_vector_type(8))) short bf16x8;   // 8 bf16 = 4 VGPRs
typedef __attribute__((ext_vector_type(4))) float f32x4;

#define DEVINL static __device__ __forceinline__

DEVINL unsigned short f2bf(float f) {
  union { float f; unsigned u; } v; v.f = f;
  unsigned r = v.u + 0x7FFF + ((v.u >> 16) & 1);  // RNE
  return (unsigned short)(r >> 16);
}
DEVINL float bf2f(unsigned short b) {
  union { unsigned u; float f; } v; v.u = ((unsigned)b) << 16; return v.f;
}

DEVINL void async16(const void* g, void* l) {
  __builtin_amdgcn_global_load_lds(
      (const __attribute__((address_space(1))) void*)g,
      (__attribute__((address_space(3))) void*)l, 16, 0, 0);
}

// ---------------- small kernels ----------------

__global__ void k_f32_to_bf16(const float* __restrict__ in,
                              unsigned short* __restrict__ out, int n) {
  int i = blockIdx.x * 256 + threadIdx.x;
  if (i < n) out[i] = f2bf(in[i]);
}

__global__ void k_zero_f32(float* __restrict__ p, int n) {
  int i = blockIdx.x * 256 + threadIdx.x;
  if (i < n) p[i] = 0.f;
}

// out[n][k] = bf16(in[k][n]); in is R x C fp32, out is C x R bf16
__global__ void k_transpose_bf16(const float* __restrict__ in,
                                 unsigned short* __restrict__ out,
                                 int R, int C) {
  __shared__ float tile[32][33];
  int c0 = blockIdx.x * 32, r0 = blockIdx.y * 32;
  int tx = threadIdx.x, ty = threadIdx.y;  // block (32,8)
#pragma unroll
  for (int i = 0; i < 4; i++)
    tile[ty + i * 8][tx] = in[(size_t)(r0 + ty + i * 8) * C + c0 + tx];
  __syncthreads();
#pragma unroll
  for (int i = 0; i < 4; i++)
    out[(size_t)(c0 + ty + i * 8) * R + r0 + tx] = f2bf(tile[tx][ty + i * 8]);
}

// lpbf[i] = bf16(lp_f32[i] + bl[i % 1536])
__global__ void k_lp_finish(const float* __restrict__ lp_f32,
                            const float* __restrict__ bl,
                            unsigned short* __restrict__ lpbf, int n) {
  int i = blockIdx.x * 256 + threadIdx.x;
  if (i < n) lpbf[i] = f2bf(lp_f32[i] + bl[i % H2]);
}

// X[bc][s][h] = tb[b][s][h] * lb[b][c][h]
__global__ void k_make_x(const unsigned short* __restrict__ tp,
                         const unsigned short* __restrict__ lp,
                         unsigned short* __restrict__ X) {
  int idx = blockIdx.x * 256 + threadIdx.x;   // total = 50*512*96
  if (idx >= CC * BB * SS * (HH / 8)) return;
  int hc = idx % (HH / 8);
  int rest = idx / (HH / 8);
  int s = rest % SS;
  int bc = rest / SS;
  int b = bc / CC;
  const bf16x8 tv = *(const bf16x8*)&tp[(size_t)(b * SS + s) * H2 + HH + hc * 8];
  const bf16x8 lv = *(const bf16x8*)&lp[(size_t)bc * H2 + HH + hc * 8];
  bf16x8 o;
#pragma unroll
  for (int j = 0; j < 8; j++) {
    float f = bf2f((unsigned short)tv[j]) * bf2f((unsigned short)lv[j]);
    o[j] = (short)f2bf(f);
  }
  *(bf16x8*)&X[(size_t)(bc * SS + s) * HH + hc * 8] = o;
}

__global__ void k_init_out(float* __restrict__ out, const float* __restrict__ b2, int n) {
  int i = blockIdx.x * 256 + threadIdx.x;
  if (i < n) out[i] = b2[i % 3];
}

// ---------------- 128x128 bf16 MFMA GEMM, BK=64, single-buffer prefetch ----
// A: M x K row-major bf16 (lda), Bt: N x K row-major bf16 (ldb)
// MODE 0: Cbf[row*ldc+col] = bf16(acc + bias[col])
// MODE 1: Cf [row*ldc+col] = acc
// MODE 3: atomicAdd(&Cf[row*ldc+col], acc)   (split-K via blockIdx.z, Klen per chunk)

template <int MODE>
__global__ __launch_bounds__(256, 3) void gemm_main(
    const unsigned short* __restrict__ A, int lda,
    const unsigned short* __restrict__ Bt, int ldb,
    int M, int Klen,
    unsigned short* __restrict__ Cbf, float* __restrict__ Cf, int ldc,
    const float* __restrict__ bias) {
  __shared__ __align__(16) unsigned short As[8 * 128 * 8];  // [kc(8)][row(128)][8]
  __shared__ __align__(16) unsigned short Bs[8 * 128 * 8];

  const int tid = threadIdx.x;
  const int lane = tid & 63;
  const int wave = tid >> 6;
  const int q = lane >> 4;
  const int li = lane & 15;
  const int wm = (wave >> 1) * 64;
  const int wn = (wave & 1) * 64;

  const int n0 = blockIdx.x * 128;
  const int m0 = blockIdx.y * 128;
  const int kofs = blockIdx.z * Klen;

  // staging: t=0..3; slot = t*256+tid; r = tid&127 (const), kc = 2t + (tid>>7)
  const int r = tid & 127;
  const int kcb = (tid >> 7) * 8;  // k elements
  const int ra = min(m0 + r, M - 1);
  const unsigned short* gA = A + (size_t)ra * lda + kcb + kofs;
  const unsigned short* gB = Bt + (size_t)(n0 + r) * ldb + kcb + kofs;
  char* lA = (char*)As + tid * 16;
  char* lB = (char*)Bs + tid * 16;

  f32x4 acc[4][4];
#pragma unroll
  for (int i = 0; i < 4; i++)
#pragma unroll
    for (int j = 0; j < 4; j++) acc[i][j] = (f32x4){0.f, 0.f, 0.f, 0.f};

  const unsigned short* lAf = &As[(q * 128 + wm + li) * 8];
  const unsigned short* lBf = &Bs[(q * 128 + wn + li) * 8];

  // pre-issue stage 0
#pragma unroll
  for (int t = 0; t < 4; t++) {
    async16(gA + t * 16, lA + t * 4096);
    async16(gB + t * 16, lB + t * 4096);
  }

  for (int k0 = 0; k0 < Klen; k0 += 64) {
    __syncthreads();  // stage data ready (drains vmcnt)

    bf16x8 af[2][4], bb[2][4];
#pragma unroll
    for (int ck = 0; ck < 2; ck++)
#pragma unroll
      for (int mi = 0; mi < 4; mi++) {
        af[ck][mi] = *(const bf16x8*)(lAf + ck * 4096 + mi * 128);
        bb[ck][mi] = *(const bf16x8*)(lBf + ck * 4096 + mi * 128);
      }
    __syncthreads();  // all waves done reading LDS

    if (k0 + 64 < Klen) {
#pragma unroll
      for (int t = 0; t < 4; t++) {
        async16(gA + k0 + 64 + t * 16, lA + t * 4096);
        async16(gB + k0 + 64 + t * 16, lB + t * 4096);
      }
    }

#pragma unroll
    for (int ck = 0; ck < 2; ck++)
#pragma unroll
      for (int mi = 0; mi < 4; mi++)
#pragma unroll
        for (int ni = 0; ni < 4; ni++)
          acc[mi][ni] = __builtin_amdgcn_mfma_f32_16x16x32_bf16(
              af[ck][mi], bb[ck][ni], acc[mi][ni], 0, 0, 0);
  }

  // ---------------- epilogues ----------------
#pragma unroll
  for (int mi = 0; mi < 4; mi++)
#pragma unroll
    for (int rr = 0; rr < 4; rr++) {
      int row = m0 + wm + mi * 16 + q * 4 + rr;
      if (row < M) {
#pragma unroll
        for (int ni = 0; ni < 4; ni++) {
          int col = n0 + wn + ni * 16 + li;
          if (MODE == 0)
            Cbf[(size_t)row * ldc + col] = f2bf(acc[mi][ni][rr] + bias[col]);
          else if (MODE == 1)
            Cf[(size_t)row * ldc + col] = acc[mi][ni][rr];
          else
            atomicAdd(&Cf[(size_t)row * ldc + col], acc[mi][ni][rr]);
        }
      }
    }
}

// ---------------- G5: scorer GEMM with fused epilogue -----------------------
// out[(b*512+s)*25*3 + c*3 + j] += sum_f relu(X@W1p + base + al + b1) * W2[f][j]
__global__ __launch_bounds__(256, 3) void gemm_scorer(
    const unsigned short* __restrict__ X,    // 25600 x 768
    const unsigned short* __restrict__ Bt,   // W1p^T: rows f (3072), ld 2304
    const float* __restrict__ base,          // (2*512) x 3072
    const float* __restrict__ al,            // 50 x 3072
    const float* __restrict__ b1,
    const float* __restrict__ W2,            // 3072 x 3
    float* __restrict__ out) {
  __shared__ __align__(16) unsigned short As[8 * 128 * 8];
  __shared__ __align__(16) unsigned short Bs[8 * 128 * 8];

  const int tid = threadIdx.x;
  const int lane = tid & 63;
  const int wave = tid >> 6;
  const int q = lane >> 4;
  const int li = lane & 15;
  const int wm = (wave >> 1) * 64;
  const int wn = (wave & 1) * 64;

  // XCD-aware swizzle: xcd owns m-tiles [25*xcd, 25*xcd+25); m fastest within n
  const int lin = blockIdx.x;
  const int xcd = lin & 7;
  const int j = lin >> 3;        // 0..599
  const int mloc = j % 25;
  const int nt = j / 25;         // 0..23
  const int mt = xcd * 25 + mloc;  // 0..199
  const int m0 = mt * 128;
  const int n0 = nt * 128;

  const int r = tid & 127;
  const int kcb = (tid >> 7) * 8;
  const unsigned short* gA = X + (size_t)(m0 + r) * HH + kcb;
  const unsigned short* gB = Bt + (size_t)(n0 + r) * H3 + kcb;
  char* lA = (char*)As + tid * 16;
  char* lB = (char*)Bs + tid * 16;

  f32x4 acc[4][4];
#pragma unroll
  for (int i = 0; i < 4; i++)
#pragma unroll
    for (int jj = 0; jj < 4; jj++) acc[i][jj] = (f32x4){0.f, 0.f, 0.f, 0.f};

  const unsigned short* lAf = &As[(q * 128 + wm + li) * 8];
  const unsigned short* lBf = &Bs[(q * 128 + wn + li) * 8];

#pragma unroll
  for (int t = 0; t < 4; t++) {
    async16(gA + t * 16, lA + t * 4096);
    async16(gB + t * 16, lB + t * 4096);
  }

  for (int k0 = 0; k0 < HH; k0 += 64) {
    __syncthreads();

    bf16x8 af[2][4], bb[2][4];
#pragma unroll
    for (int ck = 0; ck < 2; ck++)
#pragma unroll
      for (int mi = 0; mi < 4; mi++) {
        af[ck][mi] = *(const bf16x8*)(lAf + ck * 4096 + mi * 128);
        bb[ck][mi] = *(const bf16x8*)(lBf + ck * 4096 + mi * 128);
      }
    __syncthreads();

    if (k0 + 64 < HH) {
#pragma unroll
      for (int t = 0; t < 4; t++) {
        async16(gA + k0 + 64 + t * 16, lA + t * 4096);
        async16(gB + k0 + 64 + t * 16, lB + t * 4096);
      }
    }

#pragma unroll
    for (int ck = 0; ck < 2; ck++)
#pragma unroll
      for (int mi = 0; mi < 4; mi++)
#pragma unroll
        for (int ni = 0; ni < 4; ni++)
          acc[mi][ni] = __builtin_amdgcn_mfma_f32_16x16x32_bf16(
              af[ck][mi], bb[ck][ni], acc[mi][ni], 0, 0, 0);
  }

  // epilogue
  const int bc = m0 >> 9;            // all 128 rows share bc (512 rows per bc)
  const int b = bc / CC, c = bc % CC;
  float alb[4], w20[4], w21[4], w22[4];
  int fcol[4];
#pragma unroll
  for (int ni = 0; ni < 4; ni++) {
    int f = n0 + wn + ni * 16 + li;
    fcol[ni] = f;
    alb[ni] = al[(size_t)bc * H4 + f] + b1[f];
    w20[ni] = W2[f * 3 + 0];
    w21[ni] = W2[f * 3 + 1];
    w22[ni] = W2[f * 3 + 2];
  }
#pragma unroll
  for (int mi = 0; mi < 4; mi++)
#pragma unroll
    for (int rr = 0; rr < 4; rr++) {
      int g = m0 + wm + mi * 16 + q * 4 + rr;   // global row in X
      int s = g & 511;
      const float* brow = base + (size_t)(b * SS + s) * H4;
      float s0 = 0.f, s1 = 0.f, s2 = 0.f;
#pragma unroll
      for (int ni = 0; ni < 4; ni++) {
        float v = acc[mi][ni][rr] + brow[fcol[ni]] + alb[ni];
        v = fmaxf(v, 0.f);
        s0 = fmaf(v, w20[ni], s0);
        s1 = fmaf(v, w21[ni], s1);
        s2 = fmaf(v, w22[ni], s2);
      }
#pragma unroll
      for (int off = 1; off < 16; off <<= 1) {
        s0 += __shfl_xor(s0, off);
        s1 += __shfl_xor(s1, off);
        s2 += __shfl_xor(s2, off);
      }
      if (li == 0) {
        float* op = out + (size_t)((b * SS + s) * CC + c) * 3;
        atomicAdd(op + 0, s0);
        atomicAdd(op + 1, s1);
        atomicAdd(op + 2, s2);
      }
    }
}

// ---------------- host launch ----------------

extern "C" void kernel_launch(void* const* d_in, const int* in_sizes, int n_in,
                              void* d_out, int out_size, void* d_ws, size_t ws_size,
                              hipStream_t stream) {
  (void)in_sizes; (void)n_in; (void)ws_size;
  const float* token = (const float*)d_in[0];
  const float* label = (const float*)d_in[1];
  const float* Wt    = (const float*)d_in[2];
  const float* bt    = (const float*)d_in[3];
  const float* Wl    = (const float*)d_in[4];
  const float* bl    = (const float*)d_in[5];
  const float* W1    = (const float*)d_in[6];
  const float* b1    = (const float*)d_in[7];
  const float* W2    = (const float*)d_in[8];
  const float* b2    = (const float*)d_in[9];
  float* out = (float*)d_out;

  char* p = (char*)d_ws;
  auto alloc = [&](size_t bytes) {
    char* r = p;
    p += (bytes + 255) & ~(size_t)255;
    return r;
  };
  unsigned short* Tbf  = (unsigned short*)alloc((size_t)BB * SS * HH * 2);
  unsigned short* Lbf  = (unsigned short*)alloc((size_t)BB * CC * HH * 2);
  unsigned short* WtT  = (unsigned short*)alloc((size_t)H2 * HH * 2);
  unsigned short* WlT  = (unsigned short*)alloc((size_t)H2 * HH * 2);
  unsigned short* W1T  = (unsigned short*)alloc((size_t)H4 * H3 * 2);  // [3072][2304]
  unsigned short* tpbf = (unsigned short*)alloc((size_t)BB * SS * H2 * 2);
  unsigned short* lpbf = (unsigned short*)alloc((size_t)BB * CC * H2 * 2);
  unsigned short* Xall = (unsigned short*)alloc((size_t)BB * CC * SS * HH * 2);
  float* base   = (float*)alloc((size_t)BB * SS * H4 * 4);
  float* al     = (float*)alloc((size_t)BB * CC * H4 * 4);   // zeroed, atomics
  float* lp_f32 = (float*)alloc((size_t)BB * CC * H2 * 4);   // zeroed, atomics

  const int nT = BB * SS * HH;   // 786432
  const int nL = BB * CC * HH;   // 38400
  const int nLP = BB * CC * H2;  // 76800
  const int nAL = BB * CC * H4;  // 153600

  k_f32_to_bf16<<<(nT + 255) / 256, 256, 0, stream>>>(token, Tbf, nT);
  k_f32_to_bf16<<<(nL + 255) / 256, 256, 0, stream>>>(label, Lbf, nL);
  k_transpose_bf16<<<dim3(H2 / 32, HH / 32), dim3(32, 8), 0, stream>>>(Wt, WtT, HH, H2);
  k_transpose_bf16<<<dim3(H2 / 32, HH / 32), dim3(32, 8), 0, stream>>>(Wl, WlT, HH, H2);
  k_transpose_bf16<<<dim3(H4 / 32, H3 / 32), dim3(32, 8), 0, stream>>>(W1, W1T, H3, H4);

  // zero al + lp_f32 (contiguous in ws)
  k_zero_f32<<<(nAL + nLP + 255) / 256, 256, 0, stream>>>(al, nAL + nLP);

  // G1: tp = T @ Wt + bt  (M=1024,N=1536,K=768) -> bf16
  gemm_main<0><<<dim3(H2 / 128, (BB * SS) / 128, 1), 256, 0, stream>>>(
      Tbf, HH, WtT, HH, BB * SS, HH, tpbf, nullptr, H2, bt);
  // G2: lp_f32 += L @ Wl  (M=50,N=1536,K=768 split 4)
  gemm_main<3><<<dim3(H2 / 128, 1, 4), 256, 0, stream>>>(
      Lbf, HH, WlT, HH, BB * CC, HH / 4, nullptr, lp_f32, H2, nullptr);
  k_lp_finish<<<(nLP + 255) / 256, 256, 0, stream>>>(lp_f32, bl, lpbf, nLP);
  // G4: al += la @ W1l  (M=50,N=3072,K=768 split 4)
  gemm_main<3><<<dim3(H4 / 128, 1, 4), 256, 0, stream>>>(
      lpbf, H2, W1T + HH, H3, BB * CC, HH / 4, nullptr, al, H4, nullptr);

  // X = tb .* lb
  const int nX = BB * CC * SS * (HH / 8);
  k_make_x<<<(nX + 255) / 256, 256, 0, stream>>>(tpbf, lpbf, Xall);

  // G3: base = ta @ W1t  (M=1024,N=3072,K=768) -> fp32
  gemm_main<1><<<dim3(H4 / 128, (BB * SS) / 128, 1), 256, 0, stream>>>(
      tpbf, H2, W1T, H3, BB * SS, HH, nullptr, base, H4, nullptr);

  k_init_out<<<(out_size + 255) / 256, 256, 0, stream>>>(out, b2, out_size);

  // G5: swizzled scorer GEMM, grid = 200 m-tiles x 24 n-tiles = 4800 blocks
  gemm_scorer<<<dim3(4800), 256, 0, stream>>>(
      Xall, W1T + H2, base, al, b1, W2, out);
}